// Round 1
// baseline (2954.211 us; speedup 1.0000x reference)
//
#include <hip/hip_runtime.h>

#define NN 100000
#define NE 1600000
#define D 128
#define RT 64
#define PAD 132   // LDS row stride (floats): 132 % 32 = 4 -> 2-way bank alias (free)

// ---------------- zero agg ----------------
__global__ __launch_bounds__(256) void zero_kernel(float4* __restrict__ p, int n4) {
  int i = blockIdx.x * 256 + threadIdx.x;
  if (i < n4) p[i] = make_float4(0.f, 0.f, 0.f, 0.f);
}

// ---------------- scatter: agg[dst] += x[src] ----------------
// one thread per (edge, 4-feature chunk): 32 threads cover one edge's 128 feats
__global__ __launch_bounds__(256) void scatter_kernel(const float* __restrict__ x,
                                                      const int* __restrict__ ei,
                                                      float* __restrict__ agg) {
  int gid = blockIdx.x * 256 + threadIdx.x;   // < NE*32 = 51.2M
  int e = gid >> 5;
  if (e >= NE) return;
  int q = (gid & 31) << 2;
  int s = ei[e];        // src row
  int d = ei[NE + e];   // dst row
  const float4 v = *(const float4*)(x + (size_t)s * D + q);
  float* a = agg + (size_t)d * D + q;
  atomicAdd(a + 0, v.x);
  atomicAdd(a + 1, v.y);
  atomicAdd(a + 2, v.z);
  atomicAdd(a + 3, v.w);
}

// ---------------- fused: 3 GEMMs + ReLU + LN + residual ----------------
__global__ __launch_bounds__(256, 2) void fused_kernel(
    const float* __restrict__ x, const float* __restrict__ agg,
    const float* __restrict__ W1, const float* __restrict__ b1,
    const float* __restrict__ W2, const float* __restrict__ b2,
    const float* __restrict__ gamma, const float* __restrict__ beta,
    const float* __restrict__ Wres, const float* __restrict__ bres,
    float* __restrict__ out) {
  __shared__ float As[RT * PAD];   // 33.8 KB: x -> h0 -> h1 (reused in place)
  __shared__ float Bs[64 * D];     // 32 KB: current weight k-half

  const int t = threadIdx.x;
  const int tx = t & 15;           // col group: cols tx*8 .. tx*8+7
  const int ty = t >> 4;           // row group: rows ty*4 .. ty*4+3
  const int c0 = tx * 8;
  const int row0 = blockIdx.x * RT;

  // ---- stage x tile into As (rows beyond N zero-filled) ----
#pragma unroll
  for (int i = 0; i < 8; ++i) {
    int v = t + i * 256;           // 0..2047
    int r = v >> 5;                // 0..63
    int c4 = (v & 31) << 2;        // 0..124
    int row = row0 + r;
    float4 val = make_float4(0.f, 0.f, 0.f, 0.f);
    if (row < NN) val = *(const float4*)&x[(size_t)row * D + c4];
    *(float4*)&As[r * PAD + c4] = val;
  }

  float accR[4][8];                // x @ Wres
  float acc[4][8];                 // current GEMM accumulator
#pragma unroll
  for (int i = 0; i < 4; ++i)
#pragma unroll
    for (int j = 0; j < 8; ++j) { accR[i][j] = 0.f; acc[i][j] = 0.f; }

  auto gemm = [&](const float* __restrict__ B, float (&a_)[4][8]) {
#pragma unroll 1
    for (int kh = 0; kh < 2; ++kh) {
      __syncthreads();             // prior As writes visible / prior Bs readers done
#pragma unroll
      for (int i = 0; i < 8; ++i) {
        int v = t + i * 256;
        int k = v >> 5;
        int c4 = (v & 31) << 2;
        *(float4*)&Bs[k * D + c4] = *(const float4*)&B[(size_t)(kh * 64 + k) * D + c4];
      }
      __syncthreads();
#pragma unroll 4
      for (int kk = 0; kk < 64; ++kk) {
        int kg = kh * 64 + kk;
        float aa[4];
#pragma unroll
        for (int i = 0; i < 4; ++i) aa[i] = As[(ty * 4 + i) * PAD + kg];
        float4 u = *(const float4*)&Bs[kk * D + c0];
        float4 w = *(const float4*)&Bs[kk * D + c0 + 4];
        float bb[8] = {u.x, u.y, u.z, u.w, w.x, w.y, w.z, w.w};
#pragma unroll
        for (int i = 0; i < 4; ++i)
#pragma unroll
          for (int j = 0; j < 8; ++j) a_[i][j] += aa[i] * bb[j];
      }
    }
  };

  // ---- residual GEMM first (needs pristine x in As) ----
  gemm(Wres, accR);

  // ---- h0 = x + agg, in place ----
  __syncthreads();                 // GEMM-res readers done
#pragma unroll
  for (int i = 0; i < 8; ++i) {
    int v = t + i * 256;
    int r = v >> 5;
    int c4 = (v & 31) << 2;
    int row = row0 + r;
    if (row < NN) {
      float4 g = *(const float4*)&agg[(size_t)row * D + c4];
      float4 cur = *(float4*)&As[r * PAD + c4];
      cur.x += g.x; cur.y += g.y; cur.z += g.z; cur.w += g.w;
      *(float4*)&As[r * PAD + c4] = cur;
    }
  }
  // gemm() opens with __syncthreads()

  gemm(W1, acc);

  // ---- h1 = relu(acc + b1) -> As ----
  float4 p0 = *(const float4*)&b1[c0];
  float4 p1 = *(const float4*)&b1[c0 + 4];
  float bias[8] = {p0.x, p0.y, p0.z, p0.w, p1.x, p1.y, p1.z, p1.w};
  __syncthreads();                 // GEMM1 readers done before overwriting As
#pragma unroll
  for (int i = 0; i < 4; ++i) {
    float h[8];
#pragma unroll
    for (int j = 0; j < 8; ++j) {
      float vv = acc[i][j] + bias[j];
      h[j] = vv > 0.f ? vv : 0.f;
      acc[i][j] = 0.f;             // reset for GEMM2
    }
    *(float4*)&As[(ty * 4 + i) * PAD + c0] = make_float4(h[0], h[1], h[2], h[3]);
    *(float4*)&As[(ty * 4 + i) * PAD + c0 + 4] = make_float4(h[4], h[5], h[6], h[7]);
  }

  gemm(W2, acc);

  // ---- epilogue: +b2, LayerNorm (register/shuffle), + residual ----
  float4 q0 = *(const float4*)&b2[c0];
  float4 q1 = *(const float4*)&b2[c0 + 4];
  float4 g0 = *(const float4*)&gamma[c0];
  float4 g1 = *(const float4*)&gamma[c0 + 4];
  float4 e0 = *(const float4*)&beta[c0];
  float4 e1 = *(const float4*)&beta[c0 + 4];
  float4 r0 = *(const float4*)&bres[c0];
  float4 r1 = *(const float4*)&bres[c0 + 4];
  float b2v[8] = {q0.x, q0.y, q0.z, q0.w, q1.x, q1.y, q1.z, q1.w};
  float gv[8]  = {g0.x, g0.y, g0.z, g0.w, g1.x, g1.y, g1.z, g1.w};
  float bev[8] = {e0.x, e0.y, e0.z, e0.w, e1.x, e1.y, e1.z, e1.w};
  float brv[8] = {r0.x, r0.y, r0.z, r0.w, r1.x, r1.y, r1.z, r1.w};

#pragma unroll
  for (int i = 0; i < 4; ++i) {
    int row = row0 + ty * 4 + i;
    float h[8];
    float s = 0.f, s2 = 0.f;
#pragma unroll
    for (int j = 0; j < 8; ++j) {
      h[j] = acc[i][j] + b2v[j];
      s += h[j];
      s2 += h[j] * h[j];
    }
    // reduce across the 16-lane tx group (lanes ty*16 .. ty*16+15)
    for (int m = 1; m <= 8; m <<= 1) {
      s += __shfl_xor(s, m);
      s2 += __shfl_xor(s2, m);
    }
    float mu = s * 0.0078125f;               // /128
    float var = s2 * 0.0078125f - mu * mu;
    float rs = rsqrtf(var + 1e-5f);
    if (row < NN) {
      float o[8];
#pragma unroll
      for (int j = 0; j < 8; ++j)
        o[j] = (h[j] - mu) * rs * gv[j] + bev[j] + accR[i][j] + brv[j];
      *(float4*)&out[(size_t)row * D + c0] = make_float4(o[0], o[1], o[2], o[3]);
      *(float4*)&out[(size_t)row * D + c0 + 4] = make_float4(o[4], o[5], o[6], o[7]);
    }
  }
}

extern "C" void kernel_launch(void* const* d_in, const int* in_sizes, int n_in,
                              void* d_out, int out_size, void* d_ws, size_t ws_size,
                              hipStream_t stream) {
  const float* x     = (const float*)d_in[0];
  const int*   ei    = (const int*)d_in[1];
  const float* W1    = (const float*)d_in[2];
  const float* b1    = (const float*)d_in[3];
  const float* W2    = (const float*)d_in[4];
  const float* b2    = (const float*)d_in[5];
  const float* gamma = (const float*)d_in[6];
  const float* beta  = (const float*)d_in[7];
  const float* Wres  = (const float*)d_in[8];
  const float* bres  = (const float*)d_in[9];
  float* out = (float*)d_out;
  float* agg = (float*)d_ws;   // N*128 fp32 = 51.2 MB scratch

  int n4 = NN * D / 4;         // 3.2M float4
  zero_kernel<<<(n4 + 255) / 256, 256, 0, stream>>>((float4*)agg, n4);

  int scatter_threads = NE * 32;   // 51.2M
  scatter_kernel<<<scatter_threads / 256, 256, 0, stream>>>(x, ei, agg);

  fused_kernel<<<(NN + RT - 1) / RT, 256, 0, stream>>>(
      x, agg, W1, b1, W2, b2, gamma, beta, Wres, bres, out);
}

// Round 2
// 767.431 us; speedup vs baseline: 3.8495x; 3.8495x over previous
//
#include <hip/hip_runtime.h>

#define NN 100000
#define NE 1600000
#define D 128
#define RT 64
#define PAD 132   // LDS row stride (floats): 132%32=4 -> 2-way alias (free), 132%4=0 -> b128-aligned
#define NB 391    // ceil(NN/256)

// ---------------- zero deg ----------------
__global__ __launch_bounds__(256) void zero_deg(int* __restrict__ deg) {
  int i = blockIdx.x * 256 + threadIdx.x;
  if (i < NN) deg[i] = 0;
}

// ---------------- histogram: deg[dst]++ ----------------
__global__ __launch_bounds__(256) void hist_kernel(const int* __restrict__ ei,
                                                   int* __restrict__ deg) {
  int e = blockIdx.x * 256 + threadIdx.x;
  if (e < NE) atomicAdd(&deg[ei[NE + e]], 1);
}

// ---------------- scan pass 1: per-block sums ----------------
__global__ __launch_bounds__(256) void scan_pass1(const int* __restrict__ deg,
                                                  int* __restrict__ bsum) {
  __shared__ int s[256];
  int t = threadIdx.x;
  int i = blockIdx.x * 256 + t;
  s[t] = (i < NN) ? deg[i] : 0;
  __syncthreads();
  for (int st = 128; st > 0; st >>= 1) {
    if (t < st) s[t] += s[t + st];
    __syncthreads();
  }
  if (t == 0) bsum[blockIdx.x] = s[0];
}

// ---------------- scan pass 2: exclusive scan of block sums (1 block) ----------------
__global__ __launch_bounds__(512) void scan_pass2(int* __restrict__ bsum,
                                                  int* __restrict__ off) {
  __shared__ int s[512];
  int t = threadIdx.x;
  int v = (t < NB) ? bsum[t] : 0;
  s[t] = v;
  __syncthreads();
  for (int st = 1; st < 512; st <<= 1) {
    int add = (t >= st) ? s[t - st] : 0;
    __syncthreads();
    s[t] += add;
    __syncthreads();
  }
  if (t < NB) bsum[t] = s[t] - v;   // exclusive block base
  if (t == 0) off[NN] = s[511];     // total == NE
}

// ---------------- scan pass 3: per-element exclusive scan + base ----------------
__global__ __launch_bounds__(256) void scan_pass3(const int* __restrict__ deg,
                                                  const int* __restrict__ bsum,
                                                  int* __restrict__ off,
                                                  int* __restrict__ cursor) {
  __shared__ int s[256];
  int t = threadIdx.x;
  int i = blockIdx.x * 256 + t;
  int v = (i < NN) ? deg[i] : 0;
  s[t] = v;
  __syncthreads();
  for (int st = 1; st < 256; st <<= 1) {
    int add = (t >= st) ? s[t - st] : 0;
    __syncthreads();
    s[t] += add;
    __syncthreads();
  }
  if (i < NN) {
    int ex = s[t] - v + bsum[blockIdx.x];
    off[i] = ex;
    cursor[i] = ex;
  }
}

// ---------------- scatter edge ids into CSR order ----------------
__global__ __launch_bounds__(256) void scatter_ids(const int* __restrict__ ei,
                                                   int* __restrict__ cursor,
                                                   int* __restrict__ sortedSrc) {
  int e = blockIdx.x * 256 + threadIdx.x;
  if (e < NE) {
    int d = ei[NE + e];
    int pos = atomicAdd(&cursor[d], 1);
    sortedSrc[pos] = ei[e];
  }
}

// ---------------- fused: gather + 3 GEMMs + ReLU + LN + residual ----------------
__global__ __launch_bounds__(256, 2) void fused_kernel(
    const float* __restrict__ x,
    const int* __restrict__ off, const int* __restrict__ sortedSrc,
    const float* __restrict__ W1, const float* __restrict__ b1,
    const float* __restrict__ W2, const float* __restrict__ b2,
    const float* __restrict__ gamma, const float* __restrict__ beta,
    const float* __restrict__ Wres, const float* __restrict__ bres,
    float* __restrict__ out) {
  __shared__ float As[RT * PAD];   // x -> h0 -> h1 (reused in place)
  __shared__ float Bs[64 * D];     // current weight k-half

  const int t = threadIdx.x;
  const int tx = t & 15;           // col group: cols tx*8 .. tx*8+7
  const int ty = t >> 4;           // row group: rows ty*4 .. ty*4+3
  const int c0 = tx * 8;
  const int row0 = blockIdx.x * RT;

  // ---- stage x tile into As (rows beyond N zero-filled) ----
#pragma unroll
  for (int i = 0; i < 8; ++i) {
    int v = t + i * 256;
    int r = v >> 5;
    int c4 = (v & 31) << 2;
    int row = row0 + r;
    float4 val = make_float4(0.f, 0.f, 0.f, 0.f);
    if (row < NN) val = *(const float4*)&x[(size_t)row * D + c4];
    *(float4*)&As[r * PAD + c4] = val;
  }

  float accR[4][8];
  float acc[4][8];
#pragma unroll
  for (int i = 0; i < 4; ++i)
#pragma unroll
    for (int j = 0; j < 8; ++j) { accR[i][j] = 0.f; acc[i][j] = 0.f; }

  auto gemm = [&](const float* __restrict__ B, float (&a_)[4][8]) {
#pragma unroll 1
    for (int kh = 0; kh < 2; ++kh) {
      __syncthreads();             // prior As writes visible / prior Bs readers done
#pragma unroll
      for (int i = 0; i < 8; ++i) {
        int v = t + i * 256;
        int k = v >> 5;
        int c4 = (v & 31) << 2;
        *(float4*)&Bs[k * D + c4] = *(const float4*)&B[(size_t)(kh * 64 + k) * D + c4];
      }
      __syncthreads();
#pragma unroll 2
      for (int kk4 = 0; kk4 < 16; ++kk4) {
        // A: one b128 per row covers 4 k-values
        float4 a4[4];
#pragma unroll
        for (int i = 0; i < 4; ++i)
          a4[i] = *(const float4*)&As[(ty * 4 + i) * PAD + kh * 64 + kk4 * 4];
#pragma unroll
        for (int u = 0; u < 4; ++u) {
          int kk = kk4 * 4 + u;
          float4 b0v = *(const float4*)&Bs[kk * D + c0];
          float4 b1v = *(const float4*)&Bs[kk * D + c0 + 4];
          float bb[8] = {b0v.x, b0v.y, b0v.z, b0v.w, b1v.x, b1v.y, b1v.z, b1v.w};
          float aa[4] = {(&a4[0].x)[u], (&a4[1].x)[u], (&a4[2].x)[u], (&a4[3].x)[u]};
#pragma unroll
          for (int i = 0; i < 4; ++i)
#pragma unroll
            for (int j = 0; j < 8; ++j) a_[i][j] += aa[i] * bb[j];
        }
      }
    }
  };

  // ---- residual GEMM first (needs pristine x in As) ----
  gemm(Wres, accR);

  // ---- gather: As[r] += sum_{e in CSR[row]} x[src[e]]  (h0 = x + agg) ----
  __syncthreads();                 // GEMM-res As readers done
  {
    const int lane32 = t & 31;     // feature chunk: float4 at lane32*4
    const int rg = t >> 5;         // row subgroup 0..7
#pragma unroll 1
    for (int rb = 0; rb < 8; ++rb) {
      int r = rb * 8 + rg;
      int row = row0 + r;
      float4 a4 = make_float4(0.f, 0.f, 0.f, 0.f);
      if (row < NN) {
        int beg = off[row], end = off[row + 1];
        for (int j = beg; j < end; ++j) {
          int s = sortedSrc[j];
          const float4 v = *(const float4*)&x[(size_t)s * D + lane32 * 4];
          a4.x += v.x; a4.y += v.y; a4.z += v.z; a4.w += v.w;
        }
      }
      float* p = &As[r * PAD + lane32 * 4];
      float4 cur = *(float4*)p;
      cur.x += a4.x; cur.y += a4.y; cur.z += a4.z; cur.w += a4.w;
      *(float4*)p = cur;
    }
  }
  // gemm() opens with __syncthreads()

  gemm(W1, acc);

  // ---- h1 = relu(acc + b1) -> As ----
  float4 p0 = *(const float4*)&b1[c0];
  float4 p1 = *(const float4*)&b1[c0 + 4];
  float bias[8] = {p0.x, p0.y, p0.z, p0.w, p1.x, p1.y, p1.z, p1.w};
  __syncthreads();                 // GEMM1 As readers done before overwrite
#pragma unroll
  for (int i = 0; i < 4; ++i) {
    float h[8];
#pragma unroll
    for (int j = 0; j < 8; ++j) {
      float vv = acc[i][j] + bias[j];
      h[j] = vv > 0.f ? vv : 0.f;
      acc[i][j] = 0.f;
    }
    *(float4*)&As[(ty * 4 + i) * PAD + c0] = make_float4(h[0], h[1], h[2], h[3]);
    *(float4*)&As[(ty * 4 + i) * PAD + c0 + 4] = make_float4(h[4], h[5], h[6], h[7]);
  }

  gemm(W2, acc);

  // ---- epilogue: +b2, LayerNorm (register/shuffle), + residual ----
  float4 q0 = *(const float4*)&b2[c0];
  float4 q1 = *(const float4*)&b2[c0 + 4];
  float4 g0 = *(const float4*)&gamma[c0];
  float4 g1 = *(const float4*)&gamma[c0 + 4];
  float4 e0 = *(const float4*)&beta[c0];
  float4 e1 = *(const float4*)&beta[c0 + 4];
  float4 r0 = *(const float4*)&bres[c0];
  float4 r1 = *(const float4*)&bres[c0 + 4];
  float b2v[8] = {q0.x, q0.y, q0.z, q0.w, q1.x, q1.y, q1.z, q1.w};
  float gv[8]  = {g0.x, g0.y, g0.z, g0.w, g1.x, g1.y, g1.z, g1.w};
  float bev[8] = {e0.x, e0.y, e0.z, e0.w, e1.x, e1.y, e1.z, e1.w};
  float brv[8] = {r0.x, r0.y, r0.z, r0.w, r1.x, r1.y, r1.z, r1.w};

#pragma unroll
  for (int i = 0; i < 4; ++i) {
    int row = row0 + ty * 4 + i;
    float h[8];
    float s = 0.f, s2 = 0.f;
#pragma unroll
    for (int j = 0; j < 8; ++j) {
      h[j] = acc[i][j] + b2v[j];
      s += h[j];
      s2 += h[j] * h[j];
    }
    for (int m = 1; m <= 8; m <<= 1) {
      s += __shfl_xor(s, m);
      s2 += __shfl_xor(s2, m);
    }
    float mu = s * 0.0078125f;
    float var = s2 * 0.0078125f - mu * mu;
    float rs = rsqrtf(var + 1e-5f);
    if (row < NN) {
      float o[8];
#pragma unroll
      for (int j = 0; j < 8; ++j)
        o[j] = (h[j] - mu) * rs * gv[j] + bev[j] + accR[i][j] + brv[j];
      *(float4*)&out[(size_t)row * D + c0] = make_float4(o[0], o[1], o[2], o[3]);
      *(float4*)&out[(size_t)row * D + c0 + 4] = make_float4(o[4], o[5], o[6], o[7]);
    }
  }
}

extern "C" void kernel_launch(void* const* d_in, const int* in_sizes, int n_in,
                              void* d_out, int out_size, void* d_ws, size_t ws_size,
                              hipStream_t stream) {
  const float* x     = (const float*)d_in[0];
  const int*   ei    = (const int*)d_in[1];
  const float* W1    = (const float*)d_in[2];
  const float* b1    = (const float*)d_in[3];
  const float* W2    = (const float*)d_in[4];
  const float* b2    = (const float*)d_in[5];
  const float* gamma = (const float*)d_in[6];
  const float* beta  = (const float*)d_in[7];
  const float* Wres  = (const float*)d_in[8];
  const float* bres  = (const float*)d_in[9];
  float* out = (float*)d_out;

  // workspace layout (ints): ~7.3 MB total
  int* off       = (int*)d_ws;          // NN+1
  int* deg       = off + NN + 1;        // NN
  int* cursor    = deg + NN;            // NN
  int* bsum      = cursor + NN;         // 512
  int* sortedSrc = bsum + 512;          // NE

  zero_deg<<<NB, 256, 0, stream>>>(deg);
  hist_kernel<<<NE / 256, 256, 0, stream>>>(ei, deg);
  scan_pass1<<<NB, 256, 0, stream>>>(deg, bsum);
  scan_pass2<<<1, 512, 0, stream>>>(bsum, off);
  scan_pass3<<<NB, 256, 0, stream>>>(deg, bsum, off, cursor);
  scatter_ids<<<NE / 256, 256, 0, stream>>>(ei, cursor, sortedSrc);

  fused_kernel<<<(NN + RT - 1) / RT, 256, 0, stream>>>(
      x, off, sortedSrc, W1, b1, W2, b2, gamma, beta, Wres, bres, out);
}

// Round 3
// 555.676 us; speedup vs baseline: 5.3164x; 1.3811x over previous
//
#include <hip/hip_runtime.h>

#define NN 100000
#define NE 1600000
#define D 128
#define RT 64
#define PAD 132   // LDS row stride (floats): 2-way alias only (free), 16B-aligned
#define NB 391    // ceil(NN/256)

// ---------------- histogram: deg[dst]++ (4 edges/thread) ----------------
__global__ __launch_bounds__(256) void hist_kernel(const int* __restrict__ ei,
                                                   int* __restrict__ deg) {
  int i = blockIdx.x * 256 + threadIdx.x;
  if (i < NE / 4) {
    int4 d = ((const int4*)(ei + NE))[i];
    atomicAdd(&deg[d.x], 1);
    atomicAdd(&deg[d.y], 1);
    atomicAdd(&deg[d.z], 1);
    atomicAdd(&deg[d.w], 1);
  }
}

// ---------------- scan pass 1: per-block sums ----------------
__global__ __launch_bounds__(256) void scan_pass1(const int* __restrict__ deg,
                                                  int* __restrict__ bsum) {
  __shared__ int s[256];
  int t = threadIdx.x;
  int i = blockIdx.x * 256 + t;
  s[t] = (i < NN) ? deg[i] : 0;
  __syncthreads();
  for (int st = 128; st > 0; st >>= 1) {
    if (t < st) s[t] += s[t + st];
    __syncthreads();
  }
  if (t == 0) bsum[blockIdx.x] = s[0];
}

// ---------------- scan pass 2: exclusive scan of block sums (1 block) ----------------
__global__ __launch_bounds__(512) void scan_pass2(int* __restrict__ bsum,
                                                  int* __restrict__ off) {
  __shared__ int s[512];
  int t = threadIdx.x;
  int v = (t < NB) ? bsum[t] : 0;
  s[t] = v;
  __syncthreads();
  for (int st = 1; st < 512; st <<= 1) {
    int add = (t >= st) ? s[t - st] : 0;
    __syncthreads();
    s[t] += add;
    __syncthreads();
  }
  if (t < NB) bsum[t] = s[t] - v;   // exclusive block base
  if (t == 0) off[NN] = s[511];     // total == NE
}

// ---------------- scan pass 3: per-element exclusive scan + base ----------------
__global__ __launch_bounds__(256) void scan_pass3(const int* __restrict__ deg,
                                                  const int* __restrict__ bsum,
                                                  int* __restrict__ off,
                                                  int* __restrict__ cursor) {
  __shared__ int s[256];
  int t = threadIdx.x;
  int i = blockIdx.x * 256 + t;
  int v = (i < NN) ? deg[i] : 0;
  s[t] = v;
  __syncthreads();
  for (int st = 1; st < 256; st <<= 1) {
    int add = (t >= st) ? s[t - st] : 0;
    __syncthreads();
    s[t] += add;
    __syncthreads();
  }
  if (i < NN) {
    int ex = s[t] - v + bsum[blockIdx.x];
    off[i] = ex;
    cursor[i] = ex;
  }
}

// ---------------- scatter edge ids into CSR order (4 edges/thread) ----------------
__global__ __launch_bounds__(256) void scatter_ids(const int* __restrict__ ei,
                                                   int* __restrict__ cursor,
                                                   int* __restrict__ sortedSrc) {
  int i = blockIdx.x * 256 + threadIdx.x;
  if (i < NE / 4) {
    int4 s = ((const int4*)ei)[i];
    int4 d = ((const int4*)(ei + NE))[i];
    sortedSrc[atomicAdd(&cursor[d.x], 1)] = s.x;
    sortedSrc[atomicAdd(&cursor[d.y], 1)] = s.y;
    sortedSrc[atomicAdd(&cursor[d.z], 1)] = s.z;
    sortedSrc[atomicAdd(&cursor[d.w], 1)] = s.w;
  }
}

// ---------------- gather: h0[n] = x[n] + sum_{e in CSR[n]} x[src[e]] ----------------
// one 32-lane group per node; 4-deep unroll for MLP (4 outstanding 512B loads)
__global__ __launch_bounds__(256) void gather_kernel(const float* __restrict__ x,
                                                     const int* __restrict__ off,
                                                     const int* __restrict__ sortedSrc,
                                                     float* __restrict__ h0) {
  int g = blockIdx.x * 8 + (threadIdx.x >> 5);   // node id
  if (g >= NN) return;
  int lane = threadIdx.x & 31;
  size_t fo = (size_t)lane * 4;

  int beg = off[g], end = off[g + 1];
  float4 a0 = make_float4(0.f, 0.f, 0.f, 0.f);
  float4 a1 = a0, a2 = a0, a3 = a0;

  int j = beg;
  for (; j + 4 <= end; j += 4) {
    int s0 = sortedSrc[j];
    int s1 = sortedSrc[j + 1];
    int s2 = sortedSrc[j + 2];
    int s3 = sortedSrc[j + 3];
    float4 v0 = *(const float4*)&x[(size_t)s0 * D + fo];
    float4 v1 = *(const float4*)&x[(size_t)s1 * D + fo];
    float4 v2 = *(const float4*)&x[(size_t)s2 * D + fo];
    float4 v3 = *(const float4*)&x[(size_t)s3 * D + fo];
    a0.x += v0.x; a0.y += v0.y; a0.z += v0.z; a0.w += v0.w;
    a1.x += v1.x; a1.y += v1.y; a1.z += v1.z; a1.w += v1.w;
    a2.x += v2.x; a2.y += v2.y; a2.z += v2.z; a2.w += v2.w;
    a3.x += v3.x; a3.y += v3.y; a3.z += v3.z; a3.w += v3.w;
  }
  for (; j < end; ++j) {
    int s0 = sortedSrc[j];
    float4 v0 = *(const float4*)&x[(size_t)s0 * D + fo];
    a0.x += v0.x; a0.y += v0.y; a0.z += v0.z; a0.w += v0.w;
  }

  float4 xv = *(const float4*)&x[(size_t)g * D + fo];
  float4 r;
  r.x = xv.x + (a0.x + a1.x) + (a2.x + a3.x);
  r.y = xv.y + (a0.y + a1.y) + (a2.y + a3.y);
  r.z = xv.z + (a0.z + a1.z) + (a2.z + a3.z);
  r.w = xv.w + (a0.w + a1.w) + (a2.w + a3.w);
  *(float4*)&h0[(size_t)g * D + fo] = r;
}

// ---------------- fused: 3 GEMMs + ReLU + LN + residual ----------------
// cols per thread: [tx*4 .. tx*4+3] and [64+tx*4 .. 64+tx*4+3] (kills 4-way Bs conflict)
__global__ __launch_bounds__(256, 2) void fused_kernel(
    const float* __restrict__ x, const float* __restrict__ h0g,
    const float* __restrict__ W1, const float* __restrict__ b1,
    const float* __restrict__ W2, const float* __restrict__ b2,
    const float* __restrict__ gamma, const float* __restrict__ beta,
    const float* __restrict__ Wres, const float* __restrict__ bres,
    float* __restrict__ out) {
  __shared__ float As[RT * PAD];   // x -> h0 -> h1 (reused in place)
  __shared__ float Bs[64 * D];     // current weight k-half

  const int t = threadIdx.x;
  const int tx = t & 15;
  const int ty = t >> 4;
  const int c0 = tx * 4;           // first col chunk
  const int c1 = c0 + 64;          // second col chunk
  const int row0 = blockIdx.x * RT;

  auto stageA = [&](const float* __restrict__ src) {
#pragma unroll
    for (int i = 0; i < 8; ++i) {
      int v = t + i * 256;
      int r = v >> 5;
      int c4 = (v & 31) << 2;
      int row = row0 + r;
      float4 val = make_float4(0.f, 0.f, 0.f, 0.f);
      if (row < NN) val = *(const float4*)&src[(size_t)row * D + c4];
      *(float4*)&As[r * PAD + c4] = val;
    }
  };

  float accR[4][8];
  float acc[4][8];
#pragma unroll
  for (int i = 0; i < 4; ++i)
#pragma unroll
    for (int j = 0; j < 8; ++j) { accR[i][j] = 0.f; acc[i][j] = 0.f; }

  auto gemm = [&](const float* __restrict__ B, float (&a_)[4][8]) {
#pragma unroll 1
    for (int kh = 0; kh < 2; ++kh) {
      __syncthreads();             // prior As/Bs readers done
#pragma unroll
      for (int i = 0; i < 8; ++i) {
        int v = t + i * 256;
        int k = v >> 5;
        int c4 = (v & 31) << 2;
        *(float4*)&Bs[k * D + c4] = *(const float4*)&B[(size_t)(kh * 64 + k) * D + c4];
      }
      __syncthreads();
#pragma unroll 2
      for (int kk4 = 0; kk4 < 16; ++kk4) {
        float4 a4[4];
#pragma unroll
        for (int i = 0; i < 4; ++i)
          a4[i] = *(const float4*)&As[(ty * 4 + i) * PAD + kh * 64 + kk4 * 4];
#pragma unroll
        for (int u = 0; u < 4; ++u) {
          int kk = kk4 * 4 + u;
          float4 b0v = *(const float4*)&Bs[kk * D + c0];
          float4 b1v = *(const float4*)&Bs[kk * D + c1];
          float bb[8] = {b0v.x, b0v.y, b0v.z, b0v.w, b1v.x, b1v.y, b1v.z, b1v.w};
          float aa[4] = {(&a4[0].x)[u], (&a4[1].x)[u], (&a4[2].x)[u], (&a4[3].x)[u]};
#pragma unroll
          for (int i = 0; i < 4; ++i)
#pragma unroll
            for (int j = 0; j < 8; ++j) a_[i][j] += aa[i] * bb[j];
        }
      }
    }
  };

  // ---- residual GEMM on pristine x ----
  stageA(x);
  gemm(Wres, accR);

  // ---- stage h0 = x + agg (precomputed by gather_kernel, lives in d_out) ----
  __syncthreads();                 // Wres-gemm As readers done
  stageA(h0g);
  gemm(W1, acc);

  // ---- h1 = relu(acc + b1) -> As ----
  float4 p0 = *(const float4*)&b1[c0];
  float4 p1 = *(const float4*)&b1[c1];
  float bias[8] = {p0.x, p0.y, p0.z, p0.w, p1.x, p1.y, p1.z, p1.w};
  __syncthreads();                 // GEMM1 As readers done before overwrite
#pragma unroll
  for (int i = 0; i < 4; ++i) {
    float h[8];
#pragma unroll
    for (int j = 0; j < 8; ++j) {
      float vv = acc[i][j] + bias[j];
      h[j] = vv > 0.f ? vv : 0.f;
      acc[i][j] = 0.f;
    }
    *(float4*)&As[(ty * 4 + i) * PAD + c0] = make_float4(h[0], h[1], h[2], h[3]);
    *(float4*)&As[(ty * 4 + i) * PAD + c1] = make_float4(h[4], h[5], h[6], h[7]);
  }

  gemm(W2, acc);

  // ---- epilogue: +b2, LayerNorm (register/shuffle), + residual ----
  float4 q0 = *(const float4*)&b2[c0];
  float4 q1 = *(const float4*)&b2[c1];
  float4 g0 = *(const float4*)&gamma[c0];
  float4 g1 = *(const float4*)&gamma[c1];
  float4 e0 = *(const float4*)&beta[c0];
  float4 e1 = *(const float4*)&beta[c1];
  float4 r0 = *(const float4*)&bres[c0];
  float4 r1 = *(const float4*)&bres[c1];
  float b2v[8] = {q0.x, q0.y, q0.z, q0.w, q1.x, q1.y, q1.z, q1.w};
  float gv[8]  = {g0.x, g0.y, g0.z, g0.w, g1.x, g1.y, g1.z, g1.w};
  float bev[8] = {e0.x, e0.y, e0.z, e0.w, e1.x, e1.y, e1.z, e1.w};
  float brv[8] = {r0.x, r0.y, r0.z, r0.w, r1.x, r1.y, r1.z, r1.w};

#pragma unroll
  for (int i = 0; i < 4; ++i) {
    int row = row0 + ty * 4 + i;
    float h[8];
    float s = 0.f, s2 = 0.f;
#pragma unroll
    for (int j = 0; j < 8; ++j) {
      h[j] = acc[i][j] + b2v[j];
      s += h[j];
      s2 += h[j] * h[j];
    }
    for (int m = 1; m <= 8; m <<= 1) {
      s += __shfl_xor(s, m);
      s2 += __shfl_xor(s2, m);
    }
    float mu = s * 0.0078125f;
    float var = s2 * 0.0078125f - mu * mu;
    float rs = rsqrtf(var + 1e-5f);
    if (row < NN) {
      float o[8];
#pragma unroll
      for (int j = 0; j < 8; ++j)
        o[j] = (h[j] - mu) * rs * gv[j] + bev[j] + accR[i][j] + brv[j];
      *(float4*)&out[(size_t)row * D + c0] = make_float4(o[0], o[1], o[2], o[3]);
      *(float4*)&out[(size_t)row * D + c1] = make_float4(o[4], o[5], o[6], o[7]);
    }
  }
}

extern "C" void kernel_launch(void* const* d_in, const int* in_sizes, int n_in,
                              void* d_out, int out_size, void* d_ws, size_t ws_size,
                              hipStream_t stream) {
  const float* x     = (const float*)d_in[0];
  const int*   ei    = (const int*)d_in[1];
  const float* W1    = (const float*)d_in[2];
  const float* b1    = (const float*)d_in[3];
  const float* W2    = (const float*)d_in[4];
  const float* b2    = (const float*)d_in[5];
  const float* gamma = (const float*)d_in[6];
  const float* beta  = (const float*)d_in[7];
  const float* Wres  = (const float*)d_in[8];
  const float* bres  = (const float*)d_in[9];
  float* out = (float*)d_out;

  // workspace layout (ints): ~7.3 MB total
  int* off       = (int*)d_ws;          // NN+1
  int* deg       = off + NN + 1;        // NN
  int* cursor    = deg + NN;            // NN
  int* bsum      = cursor + NN;         // 512
  int* sortedSrc = bsum + 512;          // NE

  // h0 = x + agg is staged in d_out: gather writes it, each fused block reads
  // only its own rows before overwriting them -> no cross-block hazard.
  float* h0 = out;

  hipMemsetAsync(deg, 0, NN * sizeof(int), stream);
  hist_kernel<<<(NE / 4 + 255) / 256, 256, 0, stream>>>(ei, deg);
  scan_pass1<<<NB, 256, 0, stream>>>(deg, bsum);
  scan_pass2<<<1, 512, 0, stream>>>(bsum, off);
  scan_pass3<<<NB, 256, 0, stream>>>(deg, bsum, off, cursor);
  scatter_ids<<<(NE / 4 + 255) / 256, 256, 0, stream>>>(ei, cursor, sortedSrc);

  gather_kernel<<<(NN + 7) / 8, 256, 0, stream>>>(x, off, sortedSrc, h0);

  fused_kernel<<<(NN + RT - 1) / RT, 256, 0, stream>>>(
      x, h0, W1, b1, W2, b2, gamma, beta, Wres, bres, out);
}